// Round 1
// baseline (372.923 us; speedup 1.0000x reference)
//
#include <hip/hip_runtime.h>
#include <hip/hip_bf16.h>

// Problem constants
#define BS 16
#define NN 512
#define DD 256
#define RR 2
#define M_TOT (BS * NN)   // 8192 rows

// ---------------------------------------------------------------------------
// K0: build transposed packed masks bitsT[r][b][j][w] (w = i/64, bit = i%64)
//   mask0 (punct): punct==1 && aug!=1 ; mask1 (aug): aug==1
// grid (2 jb, 8 w, 16 b), 256 threads (j = jb*256 + tid) -> coalesced over j
// ---------------------------------------------------------------------------
__global__ __launch_bounds__(256) void masks_kernel(
    const int* __restrict__ aug, const int* __restrict__ punct,
    unsigned long long* __restrict__ bitsT) {
  int j = blockIdx.x * 256 + threadIdx.x;
  int w = blockIdx.y;
  int b = blockIdx.z;
  long base = ((long)(b * NN + w * 64)) * NN + j;
  unsigned long long m0 = 0ull, m1 = 0ull;
#pragma unroll 8
  for (int k = 0; k < 64; ++k) {
    int a = aug[base + (long)k * NN];
    int p = punct[base + (long)k * NN];
    unsigned long long bit = 1ull << k;
    if (a == 1) m1 |= bit;
    else if (p == 1) m0 |= bit;
  }
  bitsT[((0 * BS + b) * NN + j) * 8 + w] = m0;
  bitsT[((1 * BS + b) * NN + j) * 8 + w] = m1;
}

// ---------------------------------------------------------------------------
// K0b: inv_deg[r][b][j] = 1 / max(popcount, 1)
// ---------------------------------------------------------------------------
__global__ __launch_bounds__(256) void deg_kernel(
    const unsigned long long* __restrict__ bitsT, float* __restrict__ inv_deg) {
  int idx = blockIdx.x * 256 + threadIdx.x;  // over RR*BS*NN = 16384
  const unsigned long long* p = bitsT + (long)idx * 8;
  int s = 0;
#pragma unroll
  for (int w = 0; w < 8; ++w) s += __popcll(p[w]);
  if (s < 1) s = 1;
  inv_deg[idx] = 1.0f / (float)s;
}

// ---------------------------------------------------------------------------
// K1: agg[r][b][j][d] = inv_deg[r][b][j] * sum_{i in mask} x[b][i][d]
// grid (512 j, 16 b), 256 threads (d). Bit-scan loop is wave-uniform.
// ---------------------------------------------------------------------------
__global__ __launch_bounds__(256) void agg_kernel(
    const float* __restrict__ x, const unsigned long long* __restrict__ bitsT,
    const float* __restrict__ inv_deg, float* __restrict__ agg) {
  int j = blockIdx.x, b = blockIdx.y;
  int d = threadIdx.x;
  __shared__ unsigned long long words[16];
  __shared__ float sid[2];
  if (threadIdx.x < 16) {
    int r = threadIdx.x >> 3, w = threadIdx.x & 7;
    words[threadIdx.x] = bitsT[((r * BS + b) * NN + j) * 8 + w];
  }
  if (threadIdx.x < 2)
    sid[threadIdx.x] = inv_deg[(threadIdx.x * BS + b) * NN + j];
  __syncthreads();
  const float* xb = x + (long)(b * NN) * DD + d;
#pragma unroll
  for (int r = 0; r < 2; ++r) {
    float acc = 0.0f;
#pragma unroll
    for (int w = 0; w < 8; ++w) {
      unsigned long long m = words[r * 8 + w];
      while (m) {
        int k = __builtin_ctzll(m);
        m &= m - 1;
        acc += xb[(long)(w * 64 + k) * DD];
      }
    }
    agg[((long)(r * BS + b) * NN + j) * DD + d] = acc * sid[r];
  }
}

// ---------------------------------------------------------------------------
// K2: out[m][e] = elu( bias[e] + sum_k A[m][k] * B[k][e] ), K = 768 where
//   k<256:   A=x,            B=Wroot
//   256..511 A=agg[r=0],     B=Wrel[0]
//   512..767 A=agg[r=1],     B=Wrel[1]
// 64x64 tile, BK=16, 256 threads, 4x4 micro-tile.
// ---------------------------------------------------------------------------
__global__ __launch_bounds__(256) void gemm_kernel(
    const float* __restrict__ X, const float* __restrict__ AGG,
    const float* __restrict__ Wroot, const float* __restrict__ Wrel,
    const float* __restrict__ bias, float* __restrict__ out) {
  __shared__ float As[16][68];  // [kk][m], pad 68 to spread banks
  __shared__ float Bs[16][64];  // [kk][e]
  int tid = threadIdx.x;
  int tx = tid & 15, ty = tid >> 4;
  int mt = blockIdx.y, nt = blockIdx.x;
  int m_base = mt * 64, e_base = nt * 64;
  float c[4][4] = {{0.f}};

#pragma unroll 1
  for (int step = 0; step < 48; ++step) {
    int k0 = step * 16;
    int s = k0 >> 8;      // which source (0=root, 1=rel0, 2=rel1)
    int ko = k0 & 255;    // k offset within source
    const float* Aab = (s == 0) ? X : (AGG + (long)(s - 1) * M_TOT * DD);
    const float* Bsrc = (s == 0) ? Wroot : (Wrel + (long)(s - 1) * DD * DD);
    // load A tile: 64 rows x 16 k
#pragma unroll
    for (int l = 0; l < 4; ++l) {
      int m = l * 16 + (tid >> 4);
      int kk = tid & 15;
      As[kk][m] = Aab[(long)(m_base + m) * DD + ko + kk];
    }
    // load B tile: 16 k x 64 e
#pragma unroll
    for (int l = 0; l < 4; ++l) {
      int kk = l * 4 + (tid >> 6);
      int e = tid & 63;
      Bs[kk][e] = Bsrc[(long)(ko + kk) * DD + e_base + e];
    }
    __syncthreads();
#pragma unroll
    for (int kk = 0; kk < 16; ++kk) {
      float4 av = *reinterpret_cast<const float4*>(&As[kk][ty * 4]);
      float4 bv = *reinterpret_cast<const float4*>(&Bs[kk][tx * 4]);
      float a[4] = {av.x, av.y, av.z, av.w};
      float bb[4] = {bv.x, bv.y, bv.z, bv.w};
#pragma unroll
      for (int i = 0; i < 4; ++i)
#pragma unroll
        for (int jj = 0; jj < 4; ++jj) c[i][jj] += a[i] * bb[jj];
    }
    __syncthreads();
  }
  // epilogue: bias + ELU
#pragma unroll
  for (int i = 0; i < 4; ++i) {
    int mg = m_base + ty * 4 + i;
#pragma unroll
    for (int jj = 0; jj < 4; ++jj) {
      int eg = e_base + tx * 4 + jj;
      float v = c[i][jj] + bias[eg];
      out[(long)mg * DD + eg] = v > 0.0f ? v : (expf(v) - 1.0f);
    }
  }
}

extern "C" void kernel_launch(void* const* d_in, const int* in_sizes, int n_in,
                              void* d_out, int out_size, void* d_ws,
                              size_t ws_size, hipStream_t stream) {
  const float* x = (const float*)d_in[0];
  const float* w_rel1 = (const float*)d_in[1];
  const float* w_root1 = (const float*)d_in[2];
  const float* b1 = (const float*)d_in[3];
  const float* w_rel2 = (const float*)d_in[4];
  const float* w_root2 = (const float*)d_in[5];
  const float* b2 = (const float*)d_in[6];
  const int* aug = (const int*)d_in[7];
  const int* punct = (const int*)d_in[8];
  float* out = (float*)d_out;

  char* ws = (char*)d_ws;
  unsigned long long* bitsT = (unsigned long long*)ws;       // 1 MB
  float* inv_deg = (float*)(ws + (1u << 20));                // 64 KB
  float* agg = (float*)(ws + (1u << 20) + (1u << 16));       // 16 MB
  float* h = (float*)(ws + (1u << 20) + (1u << 16) + (16u << 20));  // 8 MB

  masks_kernel<<<dim3(2, 8, 16), 256, 0, stream>>>(aug, punct, bitsT);
  deg_kernel<<<64, 256, 0, stream>>>(bitsT, inv_deg);

  // layer 1
  agg_kernel<<<dim3(NN, BS), 256, 0, stream>>>(x, bitsT, inv_deg, agg);
  gemm_kernel<<<dim3(4, 128), 256, 0, stream>>>(x, agg, w_root1, w_rel1, b1, h);

  // layer 2
  agg_kernel<<<dim3(NN, BS), 256, 0, stream>>>(h, bitsT, inv_deg, agg);
  gemm_kernel<<<dim3(4, 128), 256, 0, stream>>>(h, agg, w_root2, w_rel2, b2,
                                                out);
}

// Round 2
// 241.353 us; speedup vs baseline: 1.5451x; 1.5451x over previous
//
#include <hip/hip_runtime.h>
#include <hip/hip_bf16.h>

// Problem constants
#define BS 16
#define NN 512
#define DD 256
#define RR 2
#define M_TOT (BS * NN)   // 8192 rows
#define KCAT 768          // concat K = DD * (1 + RR)

typedef __attribute__((ext_vector_type(8))) short short8;
typedef __attribute__((ext_vector_type(4))) float f32x4;

static __device__ __forceinline__ ushort f2bf(float f) {
  __hip_bfloat16 h = __float2bfloat16(f);
  return *reinterpret_cast<ushort*>(&h);
}

// ---------------------------------------------------------------------------
// K0: transposed packed masks bitsT[r][b][j][w] (w = i/64, bit = i%64)
//   mask0 (punct): punct==1 && aug!=1 ; mask1 (aug): aug==1
// ---------------------------------------------------------------------------
__global__ __launch_bounds__(256) void masks_kernel(
    const int* __restrict__ aug, const int* __restrict__ punct,
    unsigned long long* __restrict__ bitsT) {
  int j = blockIdx.x * 256 + threadIdx.x;
  int w = blockIdx.y;
  int b = blockIdx.z;
  long base = ((long)(b * NN + w * 64)) * NN + j;
  unsigned long long m0 = 0ull, m1 = 0ull;
#pragma unroll 8
  for (int k = 0; k < 64; ++k) {
    int a = aug[base + (long)k * NN];
    int p = punct[base + (long)k * NN];
    unsigned long long bit = 1ull << k;
    if (a == 1) m1 |= bit;
    else if (p == 1) m0 |= bit;
  }
  bitsT[((0 * BS + b) * NN + j) * 8 + w] = m0;
  bitsT[((1 * BS + b) * NN + j) * 8 + w] = m1;
}

// ---------------------------------------------------------------------------
// K0b: inv_deg[r][b][j] = 1 / max(popcount, 1)   (fp32, applied in epilogue)
// ---------------------------------------------------------------------------
__global__ __launch_bounds__(256) void deg_kernel(
    const unsigned long long* __restrict__ bitsT, float* __restrict__ inv_deg) {
  int idx = blockIdx.x * 256 + threadIdx.x;  // RR*BS*NN = 16384
  const unsigned long long* p = bitsT + (long)idx * 8;
  int s = 0;
#pragma unroll
  for (int w = 0; w < 8; ++w) s += __popcll(p[w]);
  if (s < 1) s = 1;
  inv_deg[idx] = 1.0f / (float)s;
}

// ---------------------------------------------------------------------------
// K0c: expand bits -> exact bf16 0/1 matrix MT[r][b][j][i]
// block per (b,j), thread t writes 2 elements (packed u32) per relation.
// ---------------------------------------------------------------------------
__global__ __launch_bounds__(256) void mt_kernel(
    const unsigned long long* __restrict__ bitsT, ushort* __restrict__ MT) {
  int j = blockIdx.x, b = blockIdx.y;
  __shared__ unsigned long long words[2][8];
  int t = threadIdx.x;
  if (t < 16) words[t >> 3][t & 7] = bitsT[((t >> 3) * BS + b) * NN * 8 + j * 8 + (t & 7)];
  __syncthreads();
  int i0 = t * 2;
  int w = i0 >> 6;
#pragma unroll
  for (int r = 0; r < 2; ++r) {
    unsigned long long v = words[r][w] >> (i0 & 63);
    unsigned int packed = ((v & 1) ? 0x3F80u : 0u) | ((v & 2) ? 0x3F800000u : 0u);
    unsigned int* row = reinterpret_cast<unsigned int*>(
        MT + ((size_t)((r * BS + b) * NN + j)) * NN);
    row[t] = packed;
  }
}

// ---------------------------------------------------------------------------
// convert x (fp32, [8192][256]) -> Abig slice 0 (bf16, row stride 768)
// ---------------------------------------------------------------------------
__global__ __launch_bounds__(256) void convert_x_kernel(
    const float* __restrict__ x, ushort* __restrict__ Abig) {
  int g = blockIdx.x * 256 + threadIdx.x;
  long base = (long)g * 4;                      // 4 elems, same row (256%4==0)
  long m = base >> 8, d = base & 255;
  float4 v = *reinterpret_cast<const float4*>(x + base);
  union { ushort u[4]; uint2 q; } pk;
  pk.u[0] = f2bf(v.x); pk.u[1] = f2bf(v.y); pk.u[2] = f2bf(v.z); pk.u[3] = f2bf(v.w);
  *reinterpret_cast<uint2*>(Abig + m * KCAT + d) = pk.q;
}

// ---------------------------------------------------------------------------
// transpose x: fp32 [b][i(512)][d(256)] -> bf16 xT [b][d][i]
// ---------------------------------------------------------------------------
__global__ __launch_bounds__(256) void transpose_x_kernel(
    const float* __restrict__ x, ushort* __restrict__ xT) {
  __shared__ float tile[32][33];
  int i0 = blockIdx.x * 32, d0 = blockIdx.y * 32, b = blockIdx.z;
  int tx = threadIdx.x, ty = threadIdx.y;
#pragma unroll
  for (int q = 0; q < 4; ++q) {
    int il = ty + q * 8;
    tile[il][tx] = x[((long)(b * NN + i0 + il)) * DD + d0 + tx];
  }
  __syncthreads();
#pragma unroll
  for (int q = 0; q < 4; ++q) {
    int dl = ty + q * 8;
    xT[((long)(b * DD + d0 + dl)) * NN + i0 + tx] = f2bf(tile[tx][dl]);
  }
}

// ---------------------------------------------------------------------------
// transpose h: bf16 [m=b*512+j][768] slice0 -> bf16 hT [b][d][j]
// ---------------------------------------------------------------------------
__global__ __launch_bounds__(256) void transpose_h_kernel(
    const ushort* __restrict__ A2, ushort* __restrict__ hT) {
  __shared__ ushort tile[32][33];
  int i0 = blockIdx.x * 32, d0 = blockIdx.y * 32, b = blockIdx.z;
  int tx = threadIdx.x, ty = threadIdx.y;
#pragma unroll
  for (int q = 0; q < 4; ++q) {
    int il = ty + q * 8;
    tile[il][tx] = A2[((long)(b * NN + i0 + il)) * KCAT + d0 + tx];
  }
  __syncthreads();
#pragma unroll
  for (int q = 0; q < 4; ++q) {
    int dl = ty + q * 8;
    hT[((long)(b * DD + d0 + dl)) * NN + i0 + tx] = tile[tx][dl];
  }
}

// ---------------------------------------------------------------------------
// build WcatT[e][k] bf16 (row stride 768): k<256 -> Wroot[k][e],
// 256..511 -> Wrel[0][k][e], 512..767 -> Wrel[1][k][e]
// ---------------------------------------------------------------------------
__global__ __launch_bounds__(256) void wcat_kernel(
    const float* __restrict__ Wroot, const float* __restrict__ Wrel,
    ushort* __restrict__ WcatT) {
  __shared__ float tile[32][33];
  int d0 = blockIdx.x * 32, e0 = blockIdx.y * 32, s = blockIdx.z;
  const float* src = (s == 0) ? Wroot : (Wrel + (long)(s - 1) * DD * DD);
  int tx = threadIdx.x, ty = threadIdx.y;
#pragma unroll
  for (int q = 0; q < 4; ++q) {
    int dl = ty + q * 8;
    tile[dl][tx] = src[((long)(d0 + dl)) * DD + e0 + tx];
  }
  __syncthreads();
#pragma unroll
  for (int q = 0; q < 4; ++q) {
    int el = ty + q * 8;
    WcatT[((long)(e0 + el)) * KCAT + s * 256 + d0 + tx] = f2bf(tile[tx][el]);
  }
}

// ---------------------------------------------------------------------------
// agg GEMM: agg[r,b][j][d] = inv_deg[r,b,j] * sum_i MT[r,b][j][i] * xT[b][d][i]
// C = A @ B^T, A=MT row (M=512,K=512), B=xT rows (N=256,K=512).
// 128x128 tile, BK=32, 4 waves, 4x4 frags of mfma 16x16x32 bf16.
// Output: bf16 into Abig[(b*512+j)*768 + 256 + r*256 + d]
// ---------------------------------------------------------------------------
__global__ __launch_bounds__(256) void agg_gemm_kernel(
    const ushort* __restrict__ MT, const ushort* __restrict__ xT,
    const float* __restrict__ inv_deg, ushort* __restrict__ Abig) {
  __shared__ ushort As[128][40];
  __shared__ ushort Bs[128][40];
  int t = threadIdx.x;
  int rb = blockIdx.z;           // r*16+b
  int r = rb >> 4, b = rb & 15;
  int m_base = blockIdx.y * 128; // j
  int n_base = blockIdx.x * 128; // d
  const ushort* Ag = MT + ((size_t)((r * BS + b) * NN + m_base)) * NN;
  const ushort* Bg = xT + ((size_t)(b * DD + n_base)) * NN;

  int wave = t >> 6, lane = t & 63;
  int wm = wave >> 1, wn = wave & 1;
  int fr = lane & 15, fq = lane >> 4;

  f32x4 acc[4][4];
#pragma unroll
  for (int i = 0; i < 4; ++i)
#pragma unroll
    for (int j = 0; j < 4; ++j) acc[i][j] = (f32x4)(0.0f);

#pragma unroll 1
  for (int kt = 0; kt < NN / 32; ++kt) {
    int k0 = kt * 32;
#pragma unroll
    for (int l = 0; l < 2; ++l) {
      int idx = l * 256 + t;
      int row = idx >> 2, col = (idx & 3) * 8;
      int4 av = *reinterpret_cast<const int4*>(Ag + (size_t)row * NN + k0 + col);
      *reinterpret_cast<int4*>(&As[row][col]) = av;
      int4 bv = *reinterpret_cast<const int4*>(Bg + (size_t)row * NN + k0 + col);
      *reinterpret_cast<int4*>(&Bs[row][col]) = bv;
    }
    __syncthreads();
    short8 a[4], bb[4];
#pragma unroll
    for (int mi = 0; mi < 4; ++mi)
      a[mi] = *reinterpret_cast<const short8*>(&As[wm * 64 + mi * 16 + fr][fq * 8]);
#pragma unroll
    for (int ni = 0; ni < 4; ++ni)
      bb[ni] = *reinterpret_cast<const short8*>(&Bs[wn * 64 + ni * 16 + fr][fq * 8]);
#pragma unroll
    for (int mi = 0; mi < 4; ++mi)
#pragma unroll
      for (int ni = 0; ni < 4; ++ni)
        acc[mi][ni] = __builtin_amdgcn_mfma_f32_16x16x32_bf16(a[mi], bb[ni],
                                                              acc[mi][ni], 0, 0, 0);
    __syncthreads();
  }

  // epilogue: * inv_deg (fp32), -> bf16 into Abig slice
  const float* idg = inv_deg + (r * BS + b) * NN;
#pragma unroll
  for (int mi = 0; mi < 4; ++mi) {
#pragma unroll
    for (int t4 = 0; t4 < 4; ++t4) {
      int j = m_base + wm * 64 + mi * 16 + fq * 4 + t4;
      float idv = idg[j];
      size_t rowoff = (size_t)(b * NN + j) * KCAT + 256 + r * 256;
#pragma unroll
      for (int ni = 0; ni < 4; ++ni) {
        int d = n_base + wn * 64 + ni * 16 + fr;
        Abig[rowoff + d] = f2bf(acc[mi][ni][t4] * idv);
      }
    }
  }
}

// ---------------------------------------------------------------------------
// main GEMM: out[m][e] = elu(bias[e] + sum_k Abig[m][k] * WcatT[e][k])
// MODE 0: write bf16 h into hOut slice0 (stride 768). MODE 1: fp32 out.
// ---------------------------------------------------------------------------
template <int MODE>
__global__ __launch_bounds__(256) void main_gemm_kernel(
    const ushort* __restrict__ A, const ushort* __restrict__ WcatT,
    const float* __restrict__ bias, ushort* __restrict__ hOut,
    float* __restrict__ fOut) {
  __shared__ ushort As[128][40];
  __shared__ ushort Bs[128][40];
  int t = threadIdx.x;
  int m_base = blockIdx.y * 128;
  int n_base = blockIdx.x * 128;
  const ushort* Ag = A + (size_t)m_base * KCAT;
  const ushort* Bg = WcatT + (size_t)n_base * KCAT;

  int wave = t >> 6, lane = t & 63;
  int wm = wave >> 1, wn = wave & 1;
  int fr = lane & 15, fq = lane >> 4;

  f32x4 acc[4][4];
#pragma unroll
  for (int i = 0; i < 4; ++i)
#pragma unroll
    for (int j = 0; j < 4; ++j) acc[i][j] = (f32x4)(0.0f);

#pragma unroll 1
  for (int kt = 0; kt < KCAT / 32; ++kt) {
    int k0 = kt * 32;
#pragma unroll
    for (int l = 0; l < 2; ++l) {
      int idx = l * 256 + t;
      int row = idx >> 2, col = (idx & 3) * 8;
      int4 av = *reinterpret_cast<const int4*>(Ag + (size_t)row * KCAT + k0 + col);
      *reinterpret_cast<int4*>(&As[row][col]) = av;
      int4 bv = *reinterpret_cast<const int4*>(Bg + (size_t)row * KCAT + k0 + col);
      *reinterpret_cast<int4*>(&Bs[row][col]) = bv;
    }
    __syncthreads();
    short8 a[4], bb[4];
#pragma unroll
    for (int mi = 0; mi < 4; ++mi)
      a[mi] = *reinterpret_cast<const short8*>(&As[wm * 64 + mi * 16 + fr][fq * 8]);
#pragma unroll
    for (int ni = 0; ni < 4; ++ni)
      bb[ni] = *reinterpret_cast<const short8*>(&Bs[wn * 64 + ni * 16 + fr][fq * 8]);
#pragma unroll
    for (int mi = 0; mi < 4; ++mi)
#pragma unroll
      for (int ni = 0; ni < 4; ++ni)
        acc[mi][ni] = __builtin_amdgcn_mfma_f32_16x16x32_bf16(a[mi], bb[ni],
                                                              acc[mi][ni], 0, 0, 0);
    __syncthreads();
  }

#pragma unroll
  for (int mi = 0; mi < 4; ++mi) {
#pragma unroll
    for (int t4 = 0; t4 < 4; ++t4) {
      int m = m_base + wm * 64 + mi * 16 + fq * 4 + t4;
#pragma unroll
      for (int ni = 0; ni < 4; ++ni) {
        int e = n_base + wn * 64 + ni * 16 + fr;
        float v = acc[mi][ni][t4] + bias[e];
        v = v > 0.0f ? v : expm1f(v);
        if (MODE == 0)
          hOut[(size_t)m * KCAT + e] = f2bf(v);
        else
          fOut[(size_t)m * DD + e] = v;
      }
    }
  }
}

extern "C" void kernel_launch(void* const* d_in, const int* in_sizes, int n_in,
                              void* d_out, int out_size, void* d_ws,
                              size_t ws_size, hipStream_t stream) {
  const float* x = (const float*)d_in[0];
  const float* w_rel1 = (const float*)d_in[1];
  const float* w_root1 = (const float*)d_in[2];
  const float* b1 = (const float*)d_in[3];
  const float* w_rel2 = (const float*)d_in[4];
  const float* w_root2 = (const float*)d_in[5];
  const float* b2 = (const float*)d_in[6];
  const int* aug = (const int*)d_in[7];
  const int* punct = (const int*)d_in[8];
  float* out = (float*)d_out;

  char* ws = (char*)d_ws;
  size_t off = 0;
  unsigned long long* bitsT = (unsigned long long*)(ws + off); off += (size_t)RR * BS * NN * 8 * 8;      // 1 MB
  float* inv_deg = (float*)(ws + off);                         off += (size_t)RR * BS * NN * 4;          // 64 KB
  ushort* MT = (ushort*)(ws + off);                            off += (size_t)RR * BS * NN * NN * 2;     // 16 MB
  ushort* xT = (ushort*)(ws + off);                            off += (size_t)BS * DD * NN * 2;          // 4 MB (reused as hT)
  ushort* WcatT1 = (ushort*)(ws + off);                        off += (size_t)DD * KCAT * 2;             // 384 KB
  ushort* WcatT2 = (ushort*)(ws + off);                        off += (size_t)DD * KCAT * 2;             // 384 KB
  ushort* Abig1 = (ushort*)(ws + off);                         off += (size_t)M_TOT * KCAT * 2;          // 12 MB
  ushort* Abig2 = (ushort*)(ws + off);                         off += (size_t)M_TOT * KCAT * 2;          // 12 MB

  // masks + degrees + dense bf16 mask matrix
  masks_kernel<<<dim3(2, 8, 16), 256, 0, stream>>>(aug, punct, bitsT);
  deg_kernel<<<64, 256, 0, stream>>>(bitsT, inv_deg);
  mt_kernel<<<dim3(NN, BS), 256, 0, stream>>>(bitsT, MT);

  // operand prep
  convert_x_kernel<<<M_TOT * DD / 1024, 256, 0, stream>>>(x, Abig1);
  transpose_x_kernel<<<dim3(16, 8, 16), dim3(32, 8), 0, stream>>>(x, xT);
  wcat_kernel<<<dim3(8, 8, 3), dim3(32, 8), 0, stream>>>(w_root1, w_rel1, WcatT1);
  wcat_kernel<<<dim3(8, 8, 3), dim3(32, 8), 0, stream>>>(w_root2, w_rel2, WcatT2);

  // layer 1
  agg_gemm_kernel<<<dim3(2, 4, 32), 256, 0, stream>>>(MT, xT, inv_deg, Abig1);
  main_gemm_kernel<0><<<dim3(2, 64), 256, 0, stream>>>(Abig1, WcatT1, b1, Abig2, nullptr);

  // layer 2
  transpose_h_kernel<<<dim3(16, 8, 16), dim3(32, 8), 0, stream>>>(Abig2, xT);
  agg_gemm_kernel<<<dim3(2, 4, 32), 256, 0, stream>>>(MT, xT, inv_deg, Abig2);
  main_gemm_kernel<1><<<dim3(2, 64), 256, 0, stream>>>(Abig2, WcatT2, b2, nullptr, out);
}

// Round 3
// 171.100 us; speedup vs baseline: 2.1796x; 1.4106x over previous
//
#include <hip/hip_runtime.h>
#include <hip/hip_bf16.h>

// Problem constants
#define BS 16
#define NN 512
#define DD 256
#define RR 2
#define M_TOT (BS * NN)   // 8192 rows
#define KCAT 768          // concat K = DD * (1 + RR)

typedef __attribute__((ext_vector_type(8))) short short8;
typedef __attribute__((ext_vector_type(4))) float f32x4;

static __device__ __forceinline__ ushort f2bf(float f) {
  __hip_bfloat16 h = __float2bfloat16(f);
  return *reinterpret_cast<ushort*>(&h);
}

// ---------------------------------------------------------------------------
// K0: transposed packed masks bitsT[r][b][j][w] (w = i/64, bit = i%64)
//   mask0 (punct): punct==1 && aug!=1 ; mask1 (aug): aug==1
// Branchless so the compiler can batch loads (latency fix vs round 2).
// ---------------------------------------------------------------------------
__global__ __launch_bounds__(256) void masks_kernel(
    const int* __restrict__ aug, const int* __restrict__ punct,
    unsigned long long* __restrict__ bitsT) {
  int j = blockIdx.x * 256 + threadIdx.x;
  int w = blockIdx.y;
  int b = blockIdx.z;
  long base = ((long)(b * NN + w * 64)) * NN + j;
  unsigned long long m0 = 0ull, m1 = 0ull;
#pragma unroll 16
  for (int k = 0; k < 64; ++k) {
    int a = aug[base + (long)k * NN];
    int p = punct[base + (long)k * NN];
    unsigned long long isa = (unsigned long long)(a == 1);
    unsigned long long isp = (unsigned long long)((p == 1) & (a != 1));
    m1 |= isa << k;
    m0 |= isp << k;
  }
  bitsT[((0 * BS + b) * NN + j) * 8 + w] = m0;
  bitsT[((1 * BS + b) * NN + j) * 8 + w] = m1;
}

// ---------------------------------------------------------------------------
// K0c: expand bits -> exact bf16 0/1 matrix MT[r][b][j][i]; fused inv_deg.
// ---------------------------------------------------------------------------
__global__ __launch_bounds__(256) void mt_kernel(
    const unsigned long long* __restrict__ bitsT, ushort* __restrict__ MT,
    float* __restrict__ inv_deg) {
  int j = blockIdx.x, b = blockIdx.y;
  __shared__ unsigned long long words[2][8];
  int t = threadIdx.x;
  if (t < 16)
    words[t >> 3][t & 7] = bitsT[((t >> 3) * BS + b) * NN * 8 + j * 8 + (t & 7)];
  __syncthreads();
  if (t < 2) {
    int s = 0;
#pragma unroll
    for (int w = 0; w < 8; ++w) s += __popcll(words[t][w]);
    if (s < 1) s = 1;
    inv_deg[(t * BS + b) * NN + j] = 1.0f / (float)s;
  }
  int i0 = t * 2;
  int w = i0 >> 6;
#pragma unroll
  for (int r = 0; r < 2; ++r) {
    unsigned long long v = words[r][w] >> (i0 & 63);
    unsigned int packed = ((v & 1) ? 0x3F80u : 0u) | ((v & 2) ? 0x3F800000u : 0u);
    unsigned int* row = reinterpret_cast<unsigned int*>(
        MT + ((size_t)((r * BS + b) * NN + j)) * NN);
    row[t] = packed;
  }
}

// ---------------------------------------------------------------------------
// x prep (fused): x fp32 [b][i][d] -> Abig1 slice0 (bf16, stride 768)
//                              and -> xT [b][d][i] (bf16)
// ---------------------------------------------------------------------------
__global__ void xprep_kernel(const float* __restrict__ x,
                             ushort* __restrict__ Abig1,
                             ushort* __restrict__ xT) {
  __shared__ float tile[32][33];
  int i0 = blockIdx.x * 32, d0 = blockIdx.y * 32, b = blockIdx.z;
  int tx = threadIdx.x, ty = threadIdx.y;
#pragma unroll
  for (int q = 0; q < 4; ++q) {
    int il = ty + q * 8;
    tile[il][tx] = x[((long)(b * NN + i0 + il)) * DD + d0 + tx];
  }
  __syncthreads();
#pragma unroll
  for (int q = 0; q < 4; ++q) {
    int il = ty + q * 8;
    Abig1[(size_t)(b * NN + i0 + il) * KCAT + d0 + tx] = f2bf(tile[il][tx]);
  }
#pragma unroll
  for (int q = 0; q < 4; ++q) {
    int dl = ty + q * 8;
    xT[((size_t)(b * DD + d0 + dl)) * NN + i0 + tx] = f2bf(tile[tx][dl]);
  }
}

// ---------------------------------------------------------------------------
// transpose h: bf16 [m=b*512+j][768] slice0 -> bf16 hT [b][d][j]
// ---------------------------------------------------------------------------
__global__ void transpose_h_kernel(const ushort* __restrict__ A2,
                                   ushort* __restrict__ hT) {
  __shared__ ushort tile[32][33];
  int i0 = blockIdx.x * 32, d0 = blockIdx.y * 32, b = blockIdx.z;
  int tx = threadIdx.x, ty = threadIdx.y;
#pragma unroll
  for (int q = 0; q < 4; ++q) {
    int il = ty + q * 8;
    tile[il][tx] = A2[((long)(b * NN + i0 + il)) * KCAT + d0 + tx];
  }
  __syncthreads();
#pragma unroll
  for (int q = 0; q < 4; ++q) {
    int dl = ty + q * 8;
    hT[((long)(b * DD + d0 + dl)) * NN + i0 + tx] = tile[tx][dl];
  }
}

// ---------------------------------------------------------------------------
// WcatT build for BOTH layers: WcatT[e][k], k<256 -> Wroot[k][e],
// 256..511 -> Wrel[0][k][e], 512..767 -> Wrel[1][k][e]
// ---------------------------------------------------------------------------
__global__ void wcat_kernel(const float* __restrict__ wroot1,
                            const float* __restrict__ wrel1,
                            const float* __restrict__ wroot2,
                            const float* __restrict__ wrel2,
                            ushort* __restrict__ W1, ushort* __restrict__ W2) {
  __shared__ float tile[32][33];
  int z = blockIdx.z;
  int layer = z / 3, s = z % 3;
  const float* root = layer ? wroot2 : wroot1;
  const float* rel = layer ? wrel2 : wrel1;
  ushort* dst = layer ? W2 : W1;
  const float* src = (s == 0) ? root : (rel + (size_t)(s - 1) * DD * DD);
  int d0 = blockIdx.x * 32, e0 = blockIdx.y * 32;
  int tx = threadIdx.x, ty = threadIdx.y;
#pragma unroll
  for (int q = 0; q < 4; ++q) {
    int dl = ty + q * 8;
    tile[dl][tx] = src[((long)(d0 + dl)) * DD + e0 + tx];
  }
  __syncthreads();
#pragma unroll
  for (int q = 0; q < 4; ++q) {
    int el = ty + q * 8;
    dst[((size_t)(e0 + el)) * KCAT + s * 256 + d0 + tx] = f2bf(tile[tx][el]);
  }
}

// ---------------------------------------------------------------------------
// agg GEMM: agg[r,b][j][d] = inv_deg * sum_i MT[r,b][j][i] * xT[b][d][i]
// 64x64 tile, BK=32, double-buffered LDS with reg-staged prefetch.
// grid (4 d-tiles, 8 j-tiles, 32 rb) = 1024 blocks, 256 threads.
// ---------------------------------------------------------------------------
__global__ __launch_bounds__(256) void agg_gemm_kernel(
    const ushort* __restrict__ MT, const ushort* __restrict__ xT,
    const float* __restrict__ inv_deg, ushort* __restrict__ Abig) {
  __shared__ __align__(16) ushort As[2][64][40];
  __shared__ __align__(16) ushort Bs[2][64][40];
  int t = threadIdx.x;
  int rb = blockIdx.z;
  int r = rb >> 4, b = rb & 15;
  int m_base = blockIdx.y * 64;  // j
  int n_base = blockIdx.x * 64;  // d
  int row = t >> 2, col = (t & 3) * 8;
  const ushort* Ag =
      MT + ((size_t)((r * BS + b) * NN + m_base + row)) * NN + col;
  const ushort* Bg = xT + ((size_t)(b * DD + n_base + row)) * NN + col;

  int wave = t >> 6, lane = t & 63;
  int wm = wave >> 1, wn = wave & 1;
  int fr = lane & 15, fq = lane >> 4;

  f32x4 acc[2][2];
#pragma unroll
  for (int i = 0; i < 2; ++i)
#pragma unroll
    for (int jj = 0; jj < 2; ++jj) acc[i][jj] = (f32x4)(0.0f);

  int4 ra = *reinterpret_cast<const int4*>(Ag);
  int4 rbv = *reinterpret_cast<const int4*>(Bg);
  *reinterpret_cast<int4*>(&As[0][row][col]) = ra;
  *reinterpret_cast<int4*>(&Bs[0][row][col]) = rbv;
  int cur = 0;
  __syncthreads();

#pragma unroll 1
  for (int kt = 0; kt < NN / 32; ++kt) {
    int4 na, nb;
    if (kt < NN / 32 - 1) {
      na = *reinterpret_cast<const int4*>(Ag + (kt + 1) * 32);
      nb = *reinterpret_cast<const int4*>(Bg + (kt + 1) * 32);
    }
    short8 a0 = *reinterpret_cast<const short8*>(&As[cur][wm * 32 + fr][fq * 8]);
    short8 a1 = *reinterpret_cast<const short8*>(&As[cur][wm * 32 + 16 + fr][fq * 8]);
    short8 b0 = *reinterpret_cast<const short8*>(&Bs[cur][wn * 32 + fr][fq * 8]);
    short8 b1 = *reinterpret_cast<const short8*>(&Bs[cur][wn * 32 + 16 + fr][fq * 8]);
    acc[0][0] = __builtin_amdgcn_mfma_f32_16x16x32_bf16(a0, b0, acc[0][0], 0, 0, 0);
    acc[0][1] = __builtin_amdgcn_mfma_f32_16x16x32_bf16(a0, b1, acc[0][1], 0, 0, 0);
    acc[1][0] = __builtin_amdgcn_mfma_f32_16x16x32_bf16(a1, b0, acc[1][0], 0, 0, 0);
    acc[1][1] = __builtin_amdgcn_mfma_f32_16x16x32_bf16(a1, b1, acc[1][1], 0, 0, 0);
    if (kt < NN / 32 - 1) {
      *reinterpret_cast<int4*>(&As[cur ^ 1][row][col]) = na;
      *reinterpret_cast<int4*>(&Bs[cur ^ 1][row][col]) = nb;
      __syncthreads();
      cur ^= 1;
    }
  }

  const float* idg = inv_deg + (r * BS + b) * NN + m_base;
#pragma unroll
  for (int mi = 0; mi < 2; ++mi) {
#pragma unroll
    for (int t4 = 0; t4 < 4; ++t4) {
      int jl = wm * 32 + mi * 16 + fq * 4 + t4;
      float idv = idg[jl];
      size_t rowoff =
          (size_t)(b * NN + m_base + jl) * KCAT + 256 + r * 256 + n_base;
#pragma unroll
      for (int ni = 0; ni < 2; ++ni) {
        int d = wn * 32 + ni * 16 + fr;
        Abig[rowoff + d] = f2bf(acc[mi][ni][t4] * idv);
      }
    }
  }
}

// ---------------------------------------------------------------------------
// main GEMM: out[m][e] = elu(bias[e] + sum_k Abig[m][k] * WcatT[e][k])
// 64x64 tile, BK=32, dbuf prefetch. grid (4, 128) = 512 blocks.
// MODE 0: bf16 h into hOut slice0 (stride 768). MODE 1: fp32 out.
// ---------------------------------------------------------------------------
template <int MODE>
__global__ __launch_bounds__(256) void main_gemm_kernel(
    const ushort* __restrict__ A, const ushort* __restrict__ WcatT,
    const float* __restrict__ bias, ushort* __restrict__ hOut,
    float* __restrict__ fOut) {
  __shared__ __align__(16) ushort As[2][64][40];
  __shared__ __align__(16) ushort Bs[2][64][40];
  int t = threadIdx.x;
  int m_base = blockIdx.y * 64;
  int n_base = blockIdx.x * 64;
  int row = t >> 2, col = (t & 3) * 8;
  const ushort* Ag = A + (size_t)(m_base + row) * KCAT + col;
  const ushort* Bg = WcatT + (size_t)(n_base + row) * KCAT + col;

  int wave = t >> 6, lane = t & 63;
  int wm = wave >> 1, wn = wave & 1;
  int fr = lane & 15, fq = lane >> 4;

  f32x4 acc[2][2];
#pragma unroll
  for (int i = 0; i < 2; ++i)
#pragma unroll
    for (int jj = 0; jj < 2; ++jj) acc[i][jj] = (f32x4)(0.0f);

  int4 ra = *reinterpret_cast<const int4*>(Ag);
  int4 rbv = *reinterpret_cast<const int4*>(Bg);
  *reinterpret_cast<int4*>(&As[0][row][col]) = ra;
  *reinterpret_cast<int4*>(&Bs[0][row][col]) = rbv;
  int cur = 0;
  __syncthreads();

#pragma unroll 1
  for (int kt = 0; kt < KCAT / 32; ++kt) {
    int4 na, nb;
    if (kt < KCAT / 32 - 1) {
      na = *reinterpret_cast<const int4*>(Ag + (kt + 1) * 32);
      nb = *reinterpret_cast<const int4*>(Bg + (kt + 1) * 32);
    }
    short8 a0 = *reinterpret_cast<const short8*>(&As[cur][wm * 32 + fr][fq * 8]);
    short8 a1 = *reinterpret_cast<const short8*>(&As[cur][wm * 32 + 16 + fr][fq * 8]);
    short8 b0 = *reinterpret_cast<const short8*>(&Bs[cur][wn * 32 + fr][fq * 8]);
    short8 b1 = *reinterpret_cast<const short8*>(&Bs[cur][wn * 32 + 16 + fr][fq * 8]);
    acc[0][0] = __builtin_amdgcn_mfma_f32_16x16x32_bf16(a0, b0, acc[0][0], 0, 0, 0);
    acc[0][1] = __builtin_amdgcn_mfma_f32_16x16x32_bf16(a0, b1, acc[0][1], 0, 0, 0);
    acc[1][0] = __builtin_amdgcn_mfma_f32_16x16x32_bf16(a1, b0, acc[1][0], 0, 0, 0);
    acc[1][1] = __builtin_amdgcn_mfma_f32_16x16x32_bf16(a1, b1, acc[1][1], 0, 0, 0);
    if (kt < KCAT / 32 - 1) {
      *reinterpret_cast<int4*>(&As[cur ^ 1][row][col]) = na;
      *reinterpret_cast<int4*>(&Bs[cur ^ 1][row][col]) = nb;
      __syncthreads();
      cur ^= 1;
    }
  }

#pragma unroll
  for (int mi = 0; mi < 2; ++mi) {
#pragma unroll
    for (int t4 = 0; t4 < 4; ++t4) {
      int m = m_base + wm * 32 + mi * 16 + fq * 4 + t4;
#pragma unroll
      for (int ni = 0; ni < 2; ++ni) {
        int e = n_base + wn * 32 + ni * 16 + fr;
        float v = acc[mi][ni][t4] + bias[e];
        v = v > 0.0f ? v : expm1f(v);
        if (MODE == 0)
          hOut[(size_t)m * KCAT + e] = f2bf(v);
        else
          fOut[(size_t)m * DD + e] = v;
      }
    }
  }
}

extern "C" void kernel_launch(void* const* d_in, const int* in_sizes, int n_in,
                              void* d_out, int out_size, void* d_ws,
                              size_t ws_size, hipStream_t stream) {
  const float* x = (const float*)d_in[0];
  const float* w_rel1 = (const float*)d_in[1];
  const float* w_root1 = (const float*)d_in[2];
  const float* b1 = (const float*)d_in[3];
  const float* w_rel2 = (const float*)d_in[4];
  const float* w_root2 = (const float*)d_in[5];
  const float* b2 = (const float*)d_in[6];
  const int* aug = (const int*)d_in[7];
  const int* punct = (const int*)d_in[8];
  float* out = (float*)d_out;

  char* ws = (char*)d_ws;
  size_t off = 0;
  unsigned long long* bitsT = (unsigned long long*)(ws + off); off += (size_t)RR * BS * NN * 8 * 8;
  float* inv_deg = (float*)(ws + off);                         off += (size_t)RR * BS * NN * 4;
  ushort* MT = (ushort*)(ws + off);                            off += (size_t)RR * BS * NN * NN * 2;
  ushort* xT = (ushort*)(ws + off);                            off += (size_t)BS * DD * NN * 2;
  ushort* WcatT1 = (ushort*)(ws + off);                        off += (size_t)DD * KCAT * 2;
  ushort* WcatT2 = (ushort*)(ws + off);                        off += (size_t)DD * KCAT * 2;
  ushort* Abig1 = (ushort*)(ws + off);                         off += (size_t)M_TOT * KCAT * 2;
  ushort* Abig2 = (ushort*)(ws + off);                         off += (size_t)M_TOT * KCAT * 2;

  masks_kernel<<<dim3(2, 8, 16), 256, 0, stream>>>(aug, punct, bitsT);
  mt_kernel<<<dim3(NN, BS), 256, 0, stream>>>(bitsT, MT, inv_deg);

  xprep_kernel<<<dim3(16, 8, 16), dim3(32, 8), 0, stream>>>(x, Abig1, xT);
  wcat_kernel<<<dim3(8, 8, 6), dim3(32, 8), 0, stream>>>(w_root1, w_rel1,
                                                         w_root2, w_rel2,
                                                         WcatT1, WcatT2);

  // layer 1
  agg_gemm_kernel<<<dim3(4, 8, 32), 256, 0, stream>>>(MT, xT, inv_deg, Abig1);
  main_gemm_kernel<0><<<dim3(4, 128), 256, 0, stream>>>(Abig1, WcatT1, b1,
                                                        Abig2, nullptr);

  // layer 2
  transpose_h_kernel<<<dim3(16, 8, 16), dim3(32, 8), 0, stream>>>(Abig2, xT);
  agg_gemm_kernel<<<dim3(4, 8, 32), 256, 0, stream>>>(MT, xT, inv_deg, Abig2);
  main_gemm_kernel<1><<<dim3(4, 128), 256, 0, stream>>>(Abig2, WcatT2, b2,
                                                        nullptr, out);
}